// Round 4
// baseline (710.986 us; speedup 1.0000x reference)
//
#include <hip/hip_runtime.h>
#include <hip/hip_fp16.h>
#include <hip/hip_cooperative_groups.h>

namespace cg = cooperative_groups;

// layer_3d_dep_53300544143949 — MI355X (gfx950)
// B=64, C=8, O=8, M=32, K=32, NR=8, NT=8. All inputs and output FLOAT32.
// R7 structure (cooperative fusion — ws_size proven < 4.33MB, so no fp16-in-ws tiers):
//   k1a: m-mean reduce, block=(b,c), 1024 thr (4-way m-split + LDS reduce) -> mc (ws, 4MB)
//   k1b: in-place P2 transform mc -> a2pre
//   k2_fused (cooperative, grid 512 = (b, m-group-of-4), 256 thr, __launch_bounds__(256,2)):
//     phase 1: 4x the per-m pipeline; pre-BN packed fp16 in 128 VGPRs; stats atomics
//     grid.sync()  (threadfence both sides: stats atomics cross-XCD visible)
//     phase 2: read 16 stats, normalize from registers, NT-store final f32. NO k3.
//   Fallback (coop launch error): proven k2_main f32 + k3_norm_inplace path.
// ws: [0,256) stats | [256, 256+4MB) mc/a2pre f32

using u16 = unsigned short;
using u32 = unsigned int;
typedef float f32x4 __attribute__((ext_vector_type(4)));

__device__ __forceinline__ void ld8f(const float* p, float* f) {
  float4 a = *(const float4*)p;
  float4 b = *(const float4*)(p + 4);
  f[0] = a.x; f[1] = a.y; f[2] = a.z; f[3] = a.w;
  f[4] = b.x; f[5] = b.y; f[6] = b.z; f[7] = b.w;
}
__device__ __forceinline__ void st8f(float* p, const float* f) {
  *(float4*)p = make_float4(f[0], f[1], f[2], f[3]);
  *(float4*)(p + 4) = make_float4(f[4], f[5], f[6], f[7]);
}
__device__ __forceinline__ void st8f_nt(float* p, const float* f) {
  f32x4 a = {f[0], f[1], f[2], f[3]};
  f32x4 b = {f[4], f[5], f[6], f[7]};
  __builtin_nontemporal_store(a, (f32x4*)p);
  __builtin_nontemporal_store(b, (f32x4*)(p + 4));
}
__device__ __forceinline__ u16 f2h(float f) {
  __half h = __float2half_rn(f);
  return *(u16*)&h;
}
__device__ __forceinline__ float h2f(u16 x) {
  __half h = *(__half*)&x;
  return __half2float(h);
}
__device__ __forceinline__ float fast_tanh(float x) {
  float e = __expf(2.0f * x);
  return 1.0f - 2.0f / (e + 1.0f);
}

// ---------------- k1a: m-mean reduce (1024 thr, LDS reduce) ----------------
__global__ __launch_bounds__(1024) void k1a_mmean(
    const float* __restrict__ A, float* __restrict__ mcab,
    float* __restrict__ stats) {
  __shared__ float red[4][256][9];
  const int b = blockIdx.x >> 3;
  const int c = blockIdx.x & 7;
  const int tid = threadIdx.x;
  if (blockIdx.x == 0 && tid < 16) stats[tid] = 0.0f;
  const int mh = tid >> 8;
  const int jt = tid & 255;
  const float* base = A + (size_t)(b * 8 + c) * 65536 + (size_t)mh * 8 * 2048 + jt * 8;
  float acc[8];
#pragma unroll
  for (int t = 0; t < 8; ++t) acc[t] = 0.0f;
#pragma unroll
  for (int m = 0; m < 8; ++m) {
    float ar[8];
    ld8f(base + m * 2048, ar);
#pragma unroll
    for (int t = 0; t < 8; ++t) acc[t] += ar[t];
  }
#pragma unroll
  for (int t = 0; t < 8; ++t) red[mh][jt][t] = acc[t];
  __syncthreads();
  if (mh == 0) {
    float s[8];
#pragma unroll
    for (int t = 0; t < 8; ++t)
      s[t] = (red[0][jt][t] + red[1][jt][t] + red[2][jt][t] + red[3][jt][t]) *
             (1.0f / 32.0f);
    st8f(mcab + (size_t)(b * 8 + c) * 2048 + jt * 8, s);
  }
}

// ---------------- k1b: in-place P2 transform mc -> a2pre ----------------
__global__ void k1b_p2(float* __restrict__ mcab, const float* __restrict__ P2) {
  const int b = blockIdx.x >> 3;
  const int j = (blockIdx.x & 7) * 256 + threadIdx.x;
  float mc[8];
#pragma unroll
  for (int c = 0; c < 8; ++c) mc[c] = mcab[(size_t)(b * 8 + c) * 2048 + j];
  float a2[8];
#pragma unroll
  for (int o = 0; o < 8; ++o) {
    float s = 0.0f;
#pragma unroll
    for (int c = 0; c < 8; ++c) s = fmaf(P2[o * 8 + c], mc[c], s);
    a2[o] = 0.1f * s;
  }
#pragma unroll
  for (int o = 0; o < 8; ++o) mcab[(size_t)(b * 8 + o) * 2048 + j] = a2[o];
}

// ---------------- k2_fused: main + BN, cooperative ----------------
// grid 512 = (b<<3)|mg; 256 thr. Each block does m = mg*4 + {0..3}.
// Pre-BN staged as packed fp16 in 128 u32 regs; grid sync; normalize; write.
__global__ __launch_bounds__(256, 2) void k2_fused(
    const float* __restrict__ A,
    const float* __restrict__ a2pre,
    const float* __restrict__ P1,
    const float* __restrict__ P3,
    const float* __restrict__ P4,
    const float* __restrict__ P5,
    const float* __restrict__ Wq,
    const float* __restrict__ Wk,
    const float* __restrict__ gamma,
    const float* __restrict__ beta,
    float* __restrict__ outp,
    float* __restrict__ stats) {
  __shared__ float qb[8 * 260];
  __shared__ float kb[8 * 260];
  __shared__ float vb[8 * 260];
  __shared__ float a5b[8 * 260];
  __shared__ float sred[64];

  const int tid = threadIdx.x;
  const int b = blockIdx.x >> 3;
  const int mg = blockIdx.x & 7;
  const int k = tid >> 3;
  const int r = tid & 7;

  u32 stg[4][8][4];      // [mi][o][pair] packed fp16 pre-BN
  float psum[8], psq[8];
#pragma unroll
  for (int o = 0; o < 8; ++o) { psum[o] = 0.0f; psq[o] = 0.0f; }

#pragma unroll
  for (int mi = 0; mi < 4; ++mi) {
    const int m = mg * 4 + mi;

    float acc[8][8];
    float acc3[8];
    float qv[8], kv[8], vv[8];
#pragma unroll
    for (int o = 0; o < 8; ++o) {
      acc3[o] = 0.0f;
#pragma unroll
      for (int t = 0; t < 8; ++t) acc[o][t] = 0.0f;
    }
#pragma unroll
    for (int t = 0; t < 8; ++t) { qv[t] = 0.0f; kv[t] = 0.0f; vv[t] = 0.0f; }

#pragma unroll
    for (int c = 0; c < 8; ++c) {
      float ar[8];
      ld8f(A + ((size_t)((b * 8 + c) * 32 + m) * 2048 + tid * 8), ar);
      float trc[8];
#pragma unroll
      for (int t = 0; t < 8; ++t) {
        float x = ar[t];
        x += __shfl_xor(x, 1, 64);
        x += __shfl_xor(x, 2, 64);
        x += __shfl_xor(x, 4, 64);
        trc[t] = x * 0.125f;
      }
      const float mtc = (ar[0] + ar[1] + ar[2] + ar[3] +
                         ar[4] + ar[5] + ar[6] + ar[7]) * 0.125f;
#pragma unroll
      for (int o = 0; o < 8; ++o) {
        const float w1 = P1[o * 8 + c];
        const float w4 = 0.5f * P4[o * 8 + c];
        acc3[o] = fmaf(0.1f * P3[o * 8 + c], mtc, acc3[o]);
#pragma unroll
        for (int t = 0; t < 8; ++t)
          acc[o][t] = fmaf(w1, ar[t], fmaf(w4, trc[t], acc[o][t]));
      }
      const float wq = Wq[r * 8 + c];
      const float wk = Wk[r * 8 + c];
      const float wv = P5[r * 8 + c];
#pragma unroll
      for (int t = 0; t < 8; ++t) {
        qv[t] = fmaf(wq, trc[t], qv[t]);
        kv[t] = fmaf(wk, trc[t], kv[t]);
        vv[t] = fmaf(wv, trc[t], vv[t]);
      }
    }

#pragma unroll
    for (int o = 0; o < 8; ++o) {
      float a2v[8];
      ld8f(a2pre + ((size_t)(b * 8 + o) * 2048 + tid * 8), a2v);
#pragma unroll
      for (int t = 0; t < 8; ++t) acc[o][t] += a2v[t] + acc3[o];
    }

    st8f(&qb[r * 260 + k * 8], qv);
    st8f(&kb[r * 260 + k * 8], kv);
    st8f(&vb[r * 260 + k * 8], vv);
    __syncthreads();

    {
      const int o = tid >> 5;
      const int kq = (tid >> 2) & 7;
      const int lo = tid & 3;
      float qf[4][8];
#pragma unroll
      for (int kl = 0; kl < 4; ++kl)
        ld8f(&qb[o * 260 + (kq * 4 + kl) * 8], qf[kl]);
      float a5p[4][8];
#pragma unroll
      for (int kl = 0; kl < 4; ++kl)
#pragma unroll
        for (int t = 0; t < 8; ++t) a5p[kl][t] = 0.0f;

#pragma unroll
      for (int ll = 0; ll < 8; ++ll) {
        const int l = lo * 8 + ll;
        float krw[8];
        ld8f(&kb[o * 260 + l * 8], krw);
        float al[4];
#pragma unroll
        for (int kl = 0; kl < 4; ++kl) {
          float s = 0.0f;
#pragma unroll
          for (int t = 0; t < 8; ++t) s = fmaf(qf[kl][t], krw[t], s);
          al[kl] = fast_tanh(s * 0.125f);
        }
        float vrw[8];
        ld8f(&vb[o * 260 + l * 8], vrw);
#pragma unroll
        for (int kl = 0; kl < 4; ++kl)
#pragma unroll
          for (int t = 0; t < 8; ++t)
            a5p[kl][t] = fmaf(al[kl], vrw[t], a5p[kl][t]);
      }
#pragma unroll
      for (int kl = 0; kl < 4; ++kl)
#pragma unroll
        for (int t = 0; t < 8; ++t) {
          float x = a5p[kl][t];
          x += __shfl_xor(x, 1, 64);
          x += __shfl_xor(x, 2, 64);
          a5p[kl][t] = x * 0.0625f;
        }
#pragma unroll
      for (int kl = 0; kl < 4; ++kl) {
        const float w0 = lo == 0 ? a5p[kl][0] : lo == 1 ? a5p[kl][2]
                        : lo == 2 ? a5p[kl][4] : a5p[kl][6];
        const float w1 = lo == 0 ? a5p[kl][1] : lo == 1 ? a5p[kl][3]
                        : lo == 2 ? a5p[kl][5] : a5p[kl][7];
        *(float2*)&a5b[o * 260 + (kq * 4 + kl) * 8 + lo * 2] = make_float2(w0, w1);
      }
    }
    __syncthreads();

    // Epilogue: +A5, ReLU, stats, pack fp16 to registers
#pragma unroll
    for (int o = 0; o < 8; ++o) {
      float a5f[8];
      ld8f(&a5b[o * 260 + k * 8], a5f);
      float x8[8];
#pragma unroll
      for (int t = 0; t < 8; ++t) {
        float x = acc[o][t] + a5f[t];
        x = fmaxf(x, 0.0f);
        psum[o] += x;
        psq[o] = fmaf(x, x, psq[o]);
        x8[t] = x;
      }
      stg[mi][o][0] = (u32)f2h(x8[0]) | ((u32)f2h(x8[1]) << 16);
      stg[mi][o][1] = (u32)f2h(x8[2]) | ((u32)f2h(x8[3]) << 16);
      stg[mi][o][2] = (u32)f2h(x8[4]) | ((u32)f2h(x8[5]) << 16);
      stg[mi][o][3] = (u32)f2h(x8[6]) | ((u32)f2h(x8[7]) << 16);
    }
  }

  // stats: wave butterfly -> LDS -> 16 global atomics (once for all 4 m's)
#pragma unroll
  for (int o = 0; o < 8; ++o) {
    float s = psum[o], q = psq[o];
#pragma unroll
    for (int mask = 32; mask >= 1; mask >>= 1) {
      s += __shfl_xor(s, mask, 64);
      q += __shfl_xor(q, mask, 64);
    }
    psum[o] = s; psq[o] = q;
  }
  const int lane = tid & 63;
  const int wid = tid >> 6;
  if (lane == 0) {
#pragma unroll
    for (int o = 0; o < 8; ++o) {
      sred[wid * 16 + o * 2] = psum[o];
      sred[wid * 16 + o * 2 + 1] = psq[o];
    }
  }
  __syncthreads();
  if (tid < 16) {
    float s = sred[tid] + sred[16 + tid] + sred[32 + tid] + sred[48 + tid];
    atomicAdd(&stats[tid], s);
  }

  // ---- grid-wide sync: all stats atomics complete & visible ----
  __threadfence();
  cg::this_grid().sync();
  __threadfence();

  // ---- phase 2: normalize from registers, write final f32 ----
  float gg[8], shh[8];
#pragma unroll
  for (int o = 0; o < 8; ++o) {
    const float inv_n = 1.0f / 4194304.0f;
    const float mean = stats[o * 2] * inv_n;
    float var = stats[o * 2 + 1] * inv_n - mean * mean;
    var = fmaxf(var, 0.0f);
    const float inv = rsqrtf(var + 1e-5f);
    gg[o] = gamma[o] * inv;
    shh[o] = beta[o] - mean * gg[o];
  }
#pragma unroll
  for (int mi = 0; mi < 4; ++mi) {
    const int m = mg * 4 + mi;
#pragma unroll
    for (int o = 0; o < 8; ++o) {
      float f[8];
      f[0] = h2f((u16)(stg[mi][o][0] & 0xffffu));
      f[1] = h2f((u16)(stg[mi][o][0] >> 16));
      f[2] = h2f((u16)(stg[mi][o][1] & 0xffffu));
      f[3] = h2f((u16)(stg[mi][o][1] >> 16));
      f[4] = h2f((u16)(stg[mi][o][2] & 0xffffu));
      f[5] = h2f((u16)(stg[mi][o][2] >> 16));
      f[6] = h2f((u16)(stg[mi][o][3] & 0xffffu));
      f[7] = h2f((u16)(stg[mi][o][3] >> 16));
#pragma unroll
      for (int t = 0; t < 8; ++t) f[t] = fmaf(f[t], gg[o], shh[o]);
      st8f_nt(outp + ((size_t)((b * 8 + o) * 32 + m) * 2048 + tid * 8), f);
    }
  }
}

// ---------------- fallback: k2 f32 -> d_out ----------------
__global__ __launch_bounds__(256, 2) void k2_main(
    const float* __restrict__ A,
    const float* __restrict__ a2pre,
    const float* __restrict__ P1,
    const float* __restrict__ P3,
    const float* __restrict__ P4,
    const float* __restrict__ P5,
    const float* __restrict__ Wq,
    const float* __restrict__ Wk,
    float* __restrict__ outp,
    float* __restrict__ stats) {
  __shared__ float qb[8 * 260];
  __shared__ float kb[8 * 260];
  __shared__ float vb[8 * 260];
  __shared__ float a5b[8 * 260];
  __shared__ float sred[64];

  const int tid = threadIdx.x;
  const int b = blockIdx.x >> 5;
  const int m = blockIdx.x & 31;
  const int k = tid >> 3;
  const int r = tid & 7;

  float acc[8][8];
  float acc3[8];
  float qv[8], kv[8], vv[8];
#pragma unroll
  for (int o = 0; o < 8; ++o) {
    acc3[o] = 0.0f;
#pragma unroll
    for (int t = 0; t < 8; ++t) acc[o][t] = 0.0f;
  }
#pragma unroll
  for (int t = 0; t < 8; ++t) { qv[t] = 0.0f; kv[t] = 0.0f; vv[t] = 0.0f; }

#pragma unroll
  for (int c = 0; c < 8; ++c) {
    float ar[8];
    ld8f(A + ((size_t)((b * 8 + c) * 32 + m) * 2048 + tid * 8), ar);
    float trc[8];
#pragma unroll
    for (int t = 0; t < 8; ++t) {
      float x = ar[t];
      x += __shfl_xor(x, 1, 64);
      x += __shfl_xor(x, 2, 64);
      x += __shfl_xor(x, 4, 64);
      trc[t] = x * 0.125f;
    }
    const float mtc = (ar[0] + ar[1] + ar[2] + ar[3] +
                       ar[4] + ar[5] + ar[6] + ar[7]) * 0.125f;
#pragma unroll
    for (int o = 0; o < 8; ++o) {
      const float w1 = P1[o * 8 + c];
      const float w4 = 0.5f * P4[o * 8 + c];
      acc3[o] = fmaf(0.1f * P3[o * 8 + c], mtc, acc3[o]);
#pragma unroll
      for (int t = 0; t < 8; ++t)
        acc[o][t] = fmaf(w1, ar[t], fmaf(w4, trc[t], acc[o][t]));
    }
    const float wq = Wq[r * 8 + c];
    const float wk = Wk[r * 8 + c];
    const float wv = P5[r * 8 + c];
#pragma unroll
    for (int t = 0; t < 8; ++t) {
      qv[t] = fmaf(wq, trc[t], qv[t]);
      kv[t] = fmaf(wk, trc[t], kv[t]);
      vv[t] = fmaf(wv, trc[t], vv[t]);
    }
  }

#pragma unroll
  for (int o = 0; o < 8; ++o) {
    float a2v[8];
    ld8f(a2pre + ((size_t)(b * 8 + o) * 2048 + tid * 8), a2v);
#pragma unroll
    for (int t = 0; t < 8; ++t) acc[o][t] += a2v[t] + acc3[o];
  }

  st8f(&qb[r * 260 + k * 8], qv);
  st8f(&kb[r * 260 + k * 8], kv);
  st8f(&vb[r * 260 + k * 8], vv);
  __syncthreads();

  {
    const int o = tid >> 5;
    const int kq = (tid >> 2) & 7;
    const int lo = tid & 3;
    float qf[4][8];
#pragma unroll
    for (int kl = 0; kl < 4; ++kl)
      ld8f(&qb[o * 260 + (kq * 4 + kl) * 8], qf[kl]);
    float a5p[4][8];
#pragma unroll
    for (int kl = 0; kl < 4; ++kl)
#pragma unroll
      for (int t = 0; t < 8; ++t) a5p[kl][t] = 0.0f;

#pragma unroll
    for (int ll = 0; ll < 8; ++ll) {
      const int l = lo * 8 + ll;
      float krw[8];
      ld8f(&kb[o * 260 + l * 8], krw);
      float al[4];
#pragma unroll
      for (int kl = 0; kl < 4; ++kl) {
        float s = 0.0f;
#pragma unroll
        for (int t = 0; t < 8; ++t) s = fmaf(qf[kl][t], krw[t], s);
        al[kl] = fast_tanh(s * 0.125f);
      }
      float vrw[8];
      ld8f(&vb[o * 260 + l * 8], vrw);
#pragma unroll
      for (int kl = 0; kl < 4; ++kl)
#pragma unroll
        for (int t = 0; t < 8; ++t)
          a5p[kl][t] = fmaf(al[kl], vrw[t], a5p[kl][t]);
    }
#pragma unroll
    for (int kl = 0; kl < 4; ++kl)
#pragma unroll
      for (int t = 0; t < 8; ++t) {
        float x = a5p[kl][t];
        x += __shfl_xor(x, 1, 64);
        x += __shfl_xor(x, 2, 64);
        a5p[kl][t] = x * 0.0625f;
      }
#pragma unroll
    for (int kl = 0; kl < 4; ++kl) {
      const float w0 = lo == 0 ? a5p[kl][0] : lo == 1 ? a5p[kl][2]
                      : lo == 2 ? a5p[kl][4] : a5p[kl][6];
      const float w1 = lo == 0 ? a5p[kl][1] : lo == 1 ? a5p[kl][3]
                      : lo == 2 ? a5p[kl][5] : a5p[kl][7];
      *(float2*)&a5b[o * 260 + (kq * 4 + kl) * 8 + lo * 2] = make_float2(w0, w1);
    }
  }
  __syncthreads();

  float psum[8], psq[8];
#pragma unroll
  for (int o = 0; o < 8; ++o) { psum[o] = 0.0f; psq[o] = 0.0f; }
  const size_t outbase = (size_t)(b * 256 + m) * 2048 + tid * 8;
#pragma unroll
  for (int o = 0; o < 8; ++o) {
    float a5f[8];
    ld8f(&a5b[o * 260 + k * 8], a5f);
    float x8[8];
#pragma unroll
    for (int t = 0; t < 8; ++t) {
      float x = acc[o][t] + a5f[t];
      x = fmaxf(x, 0.0f);
      psum[o] += x;
      psq[o] = fmaf(x, x, psq[o]);
      x8[t] = x;
    }
    st8f(outp + (outbase + (size_t)o * 65536), x8);
  }
#pragma unroll
  for (int o = 0; o < 8; ++o) {
    float s = psum[o], q = psq[o];
#pragma unroll
    for (int mask = 32; mask >= 1; mask >>= 1) {
      s += __shfl_xor(s, mask, 64);
      q += __shfl_xor(q, mask, 64);
    }
    psum[o] = s; psq[o] = q;
  }
  const int lane = tid & 63;
  const int wid = tid >> 6;
  if (lane == 0) {
#pragma unroll
    for (int o = 0; o < 8; ++o) {
      sred[wid * 16 + o * 2] = psum[o];
      sred[wid * 16 + o * 2 + 1] = psq[o];
    }
  }
  __syncthreads();
  if (tid < 16) {
    float s = sred[tid] + sred[16 + tid] + sred[32 + tid] + sred[48 + tid];
    atomicAdd(&stats[tid], s);
  }
}

// ---------------- fallback: BN in place ----------------
__global__ void k3_norm_inplace(float* __restrict__ outp,
                                const float* __restrict__ stats,
                                const float* __restrict__ gamma,
                                const float* __restrict__ beta) {
  const int idx = blockIdx.x * 256 + threadIdx.x;
  const size_t e0 = (size_t)idx * 8;
  const int o = (int)(e0 >> 16) & 7;
  const float inv_n = 1.0f / 4194304.0f;
  const float mean = stats[o * 2] * inv_n;
  float var = stats[o * 2 + 1] * inv_n - mean * mean;
  var = fmaxf(var, 0.0f);
  const float inv = rsqrtf(var + 1e-5f);
  const float g = gamma[o] * inv;
  const float sh = beta[o] - mean * g;
  float f[8];
  ld8f(outp + e0, f);
#pragma unroll
  for (int t = 0; t < 8; ++t) f[t] = fmaf(f[t], g, sh);
  st8f_nt(outp + e0, f);
}

extern "C" void kernel_launch(void* const* d_in, const int* in_sizes, int n_in,
                              void* d_out, int out_size, void* d_ws, size_t ws_size,
                              hipStream_t stream) {
  const float* A  = (const float*)d_in[0];
  const float* P1 = (const float*)d_in[1];
  const float* P2 = (const float*)d_in[2];
  const float* P3 = (const float*)d_in[3];
  const float* P4 = (const float*)d_in[4];
  const float* P5 = (const float*)d_in[5];
  const float* Wq = (const float*)d_in[6];
  const float* Wk = (const float*)d_in[7];
  const float* gamma = (const float*)d_in[8];
  const float* beta  = (const float*)d_in[9];
  float* outp = (float*)d_out;

  float* stats = (float*)d_ws;
  float* mcab = (float*)((char*)d_ws + 256);  // 4 MB: mc then a2pre in place

  hipLaunchKernelGGL(k1a_mmean, dim3(512), dim3(1024), 0, stream, A, mcab, stats);
  hipLaunchKernelGGL(k1b_p2, dim3(512), dim3(256), 0, stream, mcab, P2);

  // Cooperative fused main+BN. On any launch error, fall back to the proven
  // two-kernel path (nothing was launched if it fails).
  void* kargs[] = {
    (void*)&A, (void*)&mcab, (void*)&P1, (void*)&P3, (void*)&P4, (void*)&P5,
    (void*)&Wq, (void*)&Wk, (void*)&gamma, (void*)&beta, (void*)&outp,
    (void*)&stats
  };
  hipError_t err = hipLaunchCooperativeKernel(
      (const void*)k2_fused, dim3(512), dim3(256), kargs, 0, stream);
  if (err != hipSuccess) {
    (void)hipGetLastError();  // clear error state
    hipLaunchKernelGGL(k2_main, dim3(2048), dim3(256), 0, stream,
                       A, mcab, P1, P3, P4, P5, Wq, Wk, outp, stats);
    hipLaunchKernelGGL(k3_norm_inplace, dim3(16384), dim3(256), 0, stream,
                       outp, stats, gamma, beta);
  }
}

// Round 5
// 648.239 us; speedup vs baseline: 1.0968x; 1.0968x over previous
//
#include <hip/hip_runtime.h>
#include <hip/hip_fp16.h>
#include <hip/hip_cooperative_groups.h>

namespace cg = cooperative_groups;

// layer_3d_dep_53300544143949 — MI355X (gfx950)
// B=64, C=8, O=8, M=32, K=32, NR=8, NT=8. All inputs and output FLOAT32.
// R8 structure (cooperative fusion, staging via d_out instead of registers):
//   R7 post-mortem: register staging (128 u32) under VGPR cap 128 spilled wholesale
//   (FETCH/WRITE +280MB each, VALUBusy 9%). Fix: stage fp16 pre-BN into the first
//   4KB of each block's OWN 8KB output chunk (b,o,m); no state held across mi.
//   k1a: m-mean reduce -> mc (ws, 4MB) + stats zero
//   k1b: in-place P2 transform mc -> a2pre
//   k2_fused (cooperative, grid 512 = (b, m-group-of-4), 256 thr, lb(256,2)):
//     phase 1: 4x per-m pipeline; per (mi,o) pack fp16 -> store 16B into own chunk;
//              stats wave-reduce + 16 atomics
//     __threadfence + grid.sync + __threadfence
//     phase 2: per chunk: read own 16B staging, __syncthreads, write 32B f32 NT.
//     Block touches only its own chunks -> no cross-block race; barrier covers the
//     within-chunk read-before-write hazard. 64MB staging stays L2/L3-resident.
//   Fallback (coop launch error): proven k2_main f32 + k3_norm_inplace (387us).
// ws: [0,256) stats | [256, 256+4MB) mc/a2pre f32   (ws_size proven in [4.19,4.33)MB)

using u16 = unsigned short;
using u32 = unsigned int;
typedef float f32x4 __attribute__((ext_vector_type(4)));

__device__ __forceinline__ void ld8f(const float* p, float* f) {
  float4 a = *(const float4*)p;
  float4 b = *(const float4*)(p + 4);
  f[0] = a.x; f[1] = a.y; f[2] = a.z; f[3] = a.w;
  f[4] = b.x; f[5] = b.y; f[6] = b.z; f[7] = b.w;
}
__device__ __forceinline__ void st8f(float* p, const float* f) {
  *(float4*)p = make_float4(f[0], f[1], f[2], f[3]);
  *(float4*)(p + 4) = make_float4(f[4], f[5], f[6], f[7]);
}
__device__ __forceinline__ void st8f_nt(float* p, const float* f) {
  f32x4 a = {f[0], f[1], f[2], f[3]};
  f32x4 b = {f[4], f[5], f[6], f[7]};
  __builtin_nontemporal_store(a, (f32x4*)p);
  __builtin_nontemporal_store(b, (f32x4*)(p + 4));
}
__device__ __forceinline__ u16 f2h(float f) {
  __half h = __float2half_rn(f);
  return *(u16*)&h;
}
__device__ __forceinline__ float h2f(u16 x) {
  __half h = *(__half*)&x;
  return __half2float(h);
}
__device__ __forceinline__ float fast_tanh(float x) {
  float e = __expf(2.0f * x);
  return 1.0f - 2.0f / (e + 1.0f);
}

// ---------------- k1a: m-mean reduce (1024 thr, LDS reduce) ----------------
__global__ __launch_bounds__(1024) void k1a_mmean(
    const float* __restrict__ A, float* __restrict__ mcab,
    float* __restrict__ stats) {
  __shared__ float red[4][256][9];
  const int b = blockIdx.x >> 3;
  const int c = blockIdx.x & 7;
  const int tid = threadIdx.x;
  if (blockIdx.x == 0 && tid < 16) stats[tid] = 0.0f;
  const int mh = tid >> 8;
  const int jt = tid & 255;
  const float* base = A + (size_t)(b * 8 + c) * 65536 + (size_t)mh * 8 * 2048 + jt * 8;
  float acc[8];
#pragma unroll
  for (int t = 0; t < 8; ++t) acc[t] = 0.0f;
#pragma unroll
  for (int m = 0; m < 8; ++m) {
    float ar[8];
    ld8f(base + m * 2048, ar);
#pragma unroll
    for (int t = 0; t < 8; ++t) acc[t] += ar[t];
  }
#pragma unroll
  for (int t = 0; t < 8; ++t) red[mh][jt][t] = acc[t];
  __syncthreads();
  if (mh == 0) {
    float s[8];
#pragma unroll
    for (int t = 0; t < 8; ++t)
      s[t] = (red[0][jt][t] + red[1][jt][t] + red[2][jt][t] + red[3][jt][t]) *
             (1.0f / 32.0f);
    st8f(mcab + (size_t)(b * 8 + c) * 2048 + jt * 8, s);
  }
}

// ---------------- k1b: in-place P2 transform mc -> a2pre ----------------
__global__ void k1b_p2(float* __restrict__ mcab, const float* __restrict__ P2) {
  const int b = blockIdx.x >> 3;
  const int j = (blockIdx.x & 7) * 256 + threadIdx.x;
  float mc[8];
#pragma unroll
  for (int c = 0; c < 8; ++c) mc[c] = mcab[(size_t)(b * 8 + c) * 2048 + j];
  float a2[8];
#pragma unroll
  for (int o = 0; o < 8; ++o) {
    float s = 0.0f;
#pragma unroll
    for (int c = 0; c < 8; ++c) s = fmaf(P2[o * 8 + c], mc[c], s);
    a2[o] = 0.1f * s;
  }
#pragma unroll
  for (int o = 0; o < 8; ++o) mcab[(size_t)(b * 8 + o) * 2048 + j] = a2[o];
}

// ---------------- k2_fused: main + BN, cooperative, d_out staging ----------------
// grid 512 = (b<<3)|mg; 256 thr. Each block does m = mg*4 + {0..3}.
__global__ __launch_bounds__(256, 2) void k2_fused(
    const float* __restrict__ A,
    const float* __restrict__ a2pre,
    const float* __restrict__ P1,
    const float* __restrict__ P3,
    const float* __restrict__ P4,
    const float* __restrict__ P5,
    const float* __restrict__ Wq,
    const float* __restrict__ Wk,
    const float* __restrict__ gamma,
    const float* __restrict__ beta,
    float* __restrict__ outp,
    float* __restrict__ stats) {
  __shared__ float qb[8 * 260];
  __shared__ float kb[8 * 260];
  __shared__ float vb[8 * 260];
  __shared__ float a5b[8 * 260];
  __shared__ float sred[64];

  const int tid = threadIdx.x;
  const int b = blockIdx.x >> 3;
  const int mg = blockIdx.x & 7;
  const int k = tid >> 3;
  const int r = tid & 7;

  float psum[8], psq[8];
#pragma unroll
  for (int o = 0; o < 8; ++o) { psum[o] = 0.0f; psq[o] = 0.0f; }

#pragma unroll 1
  for (int mi = 0; mi < 4; ++mi) {
    const int m = mg * 4 + mi;

    float acc[8][8];
    float acc3[8];
    float qv[8], kv[8], vv[8];
#pragma unroll
    for (int o = 0; o < 8; ++o) {
      acc3[o] = 0.0f;
#pragma unroll
      for (int t = 0; t < 8; ++t) acc[o][t] = 0.0f;
    }
#pragma unroll
    for (int t = 0; t < 8; ++t) { qv[t] = 0.0f; kv[t] = 0.0f; vv[t] = 0.0f; }

#pragma unroll
    for (int c = 0; c < 8; ++c) {
      float ar[8];
      ld8f(A + ((size_t)((b * 8 + c) * 32 + m) * 2048 + tid * 8), ar);
      float trc[8];
#pragma unroll
      for (int t = 0; t < 8; ++t) {
        float x = ar[t];
        x += __shfl_xor(x, 1, 64);
        x += __shfl_xor(x, 2, 64);
        x += __shfl_xor(x, 4, 64);
        trc[t] = x * 0.125f;
      }
      const float mtc = (ar[0] + ar[1] + ar[2] + ar[3] +
                         ar[4] + ar[5] + ar[6] + ar[7]) * 0.125f;
#pragma unroll
      for (int o = 0; o < 8; ++o) {
        const float w1 = P1[o * 8 + c];
        const float w4 = 0.5f * P4[o * 8 + c];
        acc3[o] = fmaf(0.1f * P3[o * 8 + c], mtc, acc3[o]);
#pragma unroll
        for (int t = 0; t < 8; ++t)
          acc[o][t] = fmaf(w1, ar[t], fmaf(w4, trc[t], acc[o][t]));
      }
      const float wq = Wq[r * 8 + c];
      const float wk = Wk[r * 8 + c];
      const float wv = P5[r * 8 + c];
#pragma unroll
      for (int t = 0; t < 8; ++t) {
        qv[t] = fmaf(wq, trc[t], qv[t]);
        kv[t] = fmaf(wk, trc[t], kv[t]);
        vv[t] = fmaf(wv, trc[t], vv[t]);
      }
    }

#pragma unroll
    for (int o = 0; o < 8; ++o) {
      float a2v[8];
      ld8f(a2pre + ((size_t)(b * 8 + o) * 2048 + tid * 8), a2v);
#pragma unroll
      for (int t = 0; t < 8; ++t) acc[o][t] += a2v[t] + acc3[o];
    }

    st8f(&qb[r * 260 + k * 8], qv);
    st8f(&kb[r * 260 + k * 8], kv);
    st8f(&vb[r * 260 + k * 8], vv);
    __syncthreads();

    {
      const int o = tid >> 5;
      const int kq = (tid >> 2) & 7;
      const int lo = tid & 3;
      float qf[4][8];
#pragma unroll
      for (int kl = 0; kl < 4; ++kl)
        ld8f(&qb[o * 260 + (kq * 4 + kl) * 8], qf[kl]);
      float a5p[4][8];
#pragma unroll
      for (int kl = 0; kl < 4; ++kl)
#pragma unroll
        for (int t = 0; t < 8; ++t) a5p[kl][t] = 0.0f;

#pragma unroll
      for (int ll = 0; ll < 8; ++ll) {
        const int l = lo * 8 + ll;
        float krw[8];
        ld8f(&kb[o * 260 + l * 8], krw);
        float al[4];
#pragma unroll
        for (int kl = 0; kl < 4; ++kl) {
          float s = 0.0f;
#pragma unroll
          for (int t = 0; t < 8; ++t) s = fmaf(qf[kl][t], krw[t], s);
          al[kl] = fast_tanh(s * 0.125f);
        }
        float vrw[8];
        ld8f(&vb[o * 260 + l * 8], vrw);
#pragma unroll
        for (int kl = 0; kl < 4; ++kl)
#pragma unroll
          for (int t = 0; t < 8; ++t)
            a5p[kl][t] = fmaf(al[kl], vrw[t], a5p[kl][t]);
      }
#pragma unroll
      for (int kl = 0; kl < 4; ++kl)
#pragma unroll
        for (int t = 0; t < 8; ++t) {
          float x = a5p[kl][t];
          x += __shfl_xor(x, 1, 64);
          x += __shfl_xor(x, 2, 64);
          a5p[kl][t] = x * 0.0625f;
        }
#pragma unroll
      for (int kl = 0; kl < 4; ++kl) {
        const float w0 = lo == 0 ? a5p[kl][0] : lo == 1 ? a5p[kl][2]
                        : lo == 2 ? a5p[kl][4] : a5p[kl][6];
        const float w1 = lo == 0 ? a5p[kl][1] : lo == 1 ? a5p[kl][3]
                        : lo == 2 ? a5p[kl][5] : a5p[kl][7];
        *(float2*)&a5b[o * 260 + (kq * 4 + kl) * 8 + lo * 2] = make_float2(w0, w1);
      }
    }
    __syncthreads();

    // Epilogue: +A5, ReLU, stats, pack fp16 -> stage into own output chunk.
    // Chunk (b,o,m) = 8KB of d_out; staging = its first 4KB, thread t at 16B*t.
#pragma unroll
    for (int o = 0; o < 8; ++o) {
      float a5f[8];
      ld8f(&a5b[o * 260 + k * 8], a5f);
      float x8[8];
#pragma unroll
      for (int t = 0; t < 8; ++t) {
        float x = acc[o][t] + a5f[t];
        x = fmaxf(x, 0.0f);
        psum[o] += x;
        psq[o] = fmaf(x, x, psq[o]);
        x8[t] = x;
      }
      uint4 u;
      u.x = (u32)f2h(x8[0]) | ((u32)f2h(x8[1]) << 16);
      u.y = (u32)f2h(x8[2]) | ((u32)f2h(x8[3]) << 16);
      u.z = (u32)f2h(x8[4]) | ((u32)f2h(x8[5]) << 16);
      u.w = (u32)f2h(x8[6]) | ((u32)f2h(x8[7]) << 16);
      const size_t Eb = (size_t)((b * 8 + o) * 32 + m) * 2048;
      *(uint4*)((u32*)outp + Eb + 4 * tid) = u;  // cached store: re-read in phase 2
    }
  }

  // stats: wave butterfly -> LDS -> 16 global atomics (once for all 4 m's)
#pragma unroll
  for (int o = 0; o < 8; ++o) {
    float s = psum[o], q = psq[o];
#pragma unroll
    for (int mask = 32; mask >= 1; mask >>= 1) {
      s += __shfl_xor(s, mask, 64);
      q += __shfl_xor(q, mask, 64);
    }
    psum[o] = s; psq[o] = q;
  }
  const int lane = tid & 63;
  const int wid = tid >> 6;
  if (lane == 0) {
#pragma unroll
    for (int o = 0; o < 8; ++o) {
      sred[wid * 16 + o * 2] = psum[o];
      sred[wid * 16 + o * 2 + 1] = psq[o];
    }
  }
  __syncthreads();
  if (tid < 16) {
    float s = sred[tid] + sred[16 + tid] + sred[32 + tid] + sred[48 + tid];
    atomicAdd(&stats[tid], s);
  }

  // ---- grid-wide sync: all stats atomics + staging stores complete & visible ----
  __threadfence();
  cg::this_grid().sync();
  __threadfence();

  // ---- phase 2: per-chunk in-place fp16 -> normalized f32 ----
  float gg[8], shh[8];
#pragma unroll
  for (int o = 0; o < 8; ++o) {
    const float inv_n = 1.0f / 4194304.0f;
    const float mean = stats[o * 2] * inv_n;
    float var = stats[o * 2 + 1] * inv_n - mean * mean;
    var = fmaxf(var, 0.0f);
    const float inv = rsqrtf(var + 1e-5f);
    gg[o] = gamma[o] * inv;
    shh[o] = beta[o] - mean * gg[o];
  }
#pragma unroll 1
  for (int mi = 0; mi < 4; ++mi) {
    const int m = mg * 4 + mi;
#pragma unroll 1
    for (int o = 0; o < 8; ++o) {
      const size_t Eb = (size_t)((b * 8 + o) * 32 + m) * 2048;
      const uint4 u = *(const uint4*)((const u32*)outp + Eb + 4 * tid);
      __syncthreads();  // all 256 threads read the 4KB staging before any write
      float f[8];
      f[0] = h2f((u16)(u.x & 0xffffu)); f[1] = h2f((u16)(u.x >> 16));
      f[2] = h2f((u16)(u.y & 0xffffu)); f[3] = h2f((u16)(u.y >> 16));
      f[4] = h2f((u16)(u.z & 0xffffu)); f[5] = h2f((u16)(u.z >> 16));
      f[6] = h2f((u16)(u.w & 0xffffu)); f[7] = h2f((u16)(u.w >> 16));
#pragma unroll
      for (int t = 0; t < 8; ++t) f[t] = fmaf(f[t], gg[o], shh[o]);
      st8f_nt(outp + Eb + (size_t)tid * 8, f);
    }
  }
}

// ---------------- fallback: k2 f32 -> d_out ----------------
__global__ __launch_bounds__(256, 2) void k2_main(
    const float* __restrict__ A,
    const float* __restrict__ a2pre,
    const float* __restrict__ P1,
    const float* __restrict__ P3,
    const float* __restrict__ P4,
    const float* __restrict__ P5,
    const float* __restrict__ Wq,
    const float* __restrict__ Wk,
    float* __restrict__ outp,
    float* __restrict__ stats) {
  __shared__ float qb[8 * 260];
  __shared__ float kb[8 * 260];
  __shared__ float vb[8 * 260];
  __shared__ float a5b[8 * 260];
  __shared__ float sred[64];

  const int tid = threadIdx.x;
  const int b = blockIdx.x >> 5;
  const int m = blockIdx.x & 31;
  const int k = tid >> 3;
  const int r = tid & 7;

  float acc[8][8];
  float acc3[8];
  float qv[8], kv[8], vv[8];
#pragma unroll
  for (int o = 0; o < 8; ++o) {
    acc3[o] = 0.0f;
#pragma unroll
    for (int t = 0; t < 8; ++t) acc[o][t] = 0.0f;
  }
#pragma unroll
  for (int t = 0; t < 8; ++t) { qv[t] = 0.0f; kv[t] = 0.0f; vv[t] = 0.0f; }

#pragma unroll
  for (int c = 0; c < 8; ++c) {
    float ar[8];
    ld8f(A + ((size_t)((b * 8 + c) * 32 + m) * 2048 + tid * 8), ar);
    float trc[8];
#pragma unroll
    for (int t = 0; t < 8; ++t) {
      float x = ar[t];
      x += __shfl_xor(x, 1, 64);
      x += __shfl_xor(x, 2, 64);
      x += __shfl_xor(x, 4, 64);
      trc[t] = x * 0.125f;
    }
    const float mtc = (ar[0] + ar[1] + ar[2] + ar[3] +
                       ar[4] + ar[5] + ar[6] + ar[7]) * 0.125f;
#pragma unroll
    for (int o = 0; o < 8; ++o) {
      const float w1 = P1[o * 8 + c];
      const float w4 = 0.5f * P4[o * 8 + c];
      acc3[o] = fmaf(0.1f * P3[o * 8 + c], mtc, acc3[o]);
#pragma unroll
      for (int t = 0; t < 8; ++t)
        acc[o][t] = fmaf(w1, ar[t], fmaf(w4, trc[t], acc[o][t]));
    }
    const float wq = Wq[r * 8 + c];
    const float wk = Wk[r * 8 + c];
    const float wv = P5[r * 8 + c];
#pragma unroll
    for (int t = 0; t < 8; ++t) {
      qv[t] = fmaf(wq, trc[t], qv[t]);
      kv[t] = fmaf(wk, trc[t], kv[t]);
      vv[t] = fmaf(wv, trc[t], vv[t]);
    }
  }

#pragma unroll
  for (int o = 0; o < 8; ++o) {
    float a2v[8];
    ld8f(a2pre + ((size_t)(b * 8 + o) * 2048 + tid * 8), a2v);
#pragma unroll
    for (int t = 0; t < 8; ++t) acc[o][t] += a2v[t] + acc3[o];
  }

  st8f(&qb[r * 260 + k * 8], qv);
  st8f(&kb[r * 260 + k * 8], kv);
  st8f(&vb[r * 260 + k * 8], vv);
  __syncthreads();

  {
    const int o = tid >> 5;
    const int kq = (tid >> 2) & 7;
    const int lo = tid & 3;
    float qf[4][8];
#pragma unroll
    for (int kl = 0; kl < 4; ++kl)
      ld8f(&qb[o * 260 + (kq * 4 + kl) * 8], qf[kl]);
    float a5p[4][8];
#pragma unroll
    for (int kl = 0; kl < 4; ++kl)
#pragma unroll
      for (int t = 0; t < 8; ++t) a5p[kl][t] = 0.0f;

#pragma unroll
    for (int ll = 0; ll < 8; ++ll) {
      const int l = lo * 8 + ll;
      float krw[8];
      ld8f(&kb[o * 260 + l * 8], krw);
      float al[4];
#pragma unroll
      for (int kl = 0; kl < 4; ++kl) {
        float s = 0.0f;
#pragma unroll
        for (int t = 0; t < 8; ++t) s = fmaf(qf[kl][t], krw[t], s);
        al[kl] = fast_tanh(s * 0.125f);
      }
      float vrw[8];
      ld8f(&vb[o * 260 + l * 8], vrw);
#pragma unroll
      for (int kl = 0; kl < 4; ++kl)
#pragma unroll
        for (int t = 0; t < 8; ++t)
          a5p[kl][t] = fmaf(al[kl], vrw[t], a5p[kl][t]);
    }
#pragma unroll
    for (int kl = 0; kl < 4; ++kl)
#pragma unroll
      for (int t = 0; t < 8; ++t) {
        float x = a5p[kl][t];
        x += __shfl_xor(x, 1, 64);
        x += __shfl_xor(x, 2, 64);
        a5p[kl][t] = x * 0.0625f;
      }
#pragma unroll
    for (int kl = 0; kl < 4; ++kl) {
      const float w0 = lo == 0 ? a5p[kl][0] : lo == 1 ? a5p[kl][2]
                      : lo == 2 ? a5p[kl][4] : a5p[kl][6];
      const float w1 = lo == 0 ? a5p[kl][1] : lo == 1 ? a5p[kl][3]
                      : lo == 2 ? a5p[kl][5] : a5p[kl][7];
      *(float2*)&a5b[o * 260 + (kq * 4 + kl) * 8 + lo * 2] = make_float2(w0, w1);
    }
  }
  __syncthreads();

  float psum[8], psq[8];
#pragma unroll
  for (int o = 0; o < 8; ++o) { psum[o] = 0.0f; psq[o] = 0.0f; }
  const size_t outbase = (size_t)(b * 256 + m) * 2048 + tid * 8;
#pragma unroll
  for (int o = 0; o < 8; ++o) {
    float a5f[8];
    ld8f(&a5b[o * 260 + k * 8], a5f);
    float x8[8];
#pragma unroll
    for (int t = 0; t < 8; ++t) {
      float x = acc[o][t] + a5f[t];
      x = fmaxf(x, 0.0f);
      psum[o] += x;
      psq[o] = fmaf(x, x, psq[o]);
      x8[t] = x;
    }
    st8f(outp + (outbase + (size_t)o * 65536), x8);
  }
#pragma unroll
  for (int o = 0; o < 8; ++o) {
    float s = psum[o], q = psq[o];
#pragma unroll
    for (int mask = 32; mask >= 1; mask >>= 1) {
      s += __shfl_xor(s, mask, 64);
      q += __shfl_xor(q, mask, 64);
    }
    psum[o] = s; psq[o] = q;
  }
  const int lane = tid & 63;
  const int wid = tid >> 6;
  if (lane == 0) {
#pragma unroll
    for (int o = 0; o < 8; ++o) {
      sred[wid * 16 + o * 2] = psum[o];
      sred[wid * 16 + o * 2 + 1] = psq[o];
    }
  }
  __syncthreads();
  if (tid < 16) {
    float s = sred[tid] + sred[16 + tid] + sred[32 + tid] + sred[48 + tid];
    atomicAdd(&stats[tid], s);
  }
}

// ---------------- fallback: BN in place ----------------
__global__ void k3_norm_inplace(float* __restrict__ outp,
                                const float* __restrict__ stats,
                                const float* __restrict__ gamma,
                                const float* __restrict__ beta) {
  const int idx = blockIdx.x * 256 + threadIdx.x;
  const size_t e0 = (size_t)idx * 8;
  const int o = (int)(e0 >> 16) & 7;
  const float inv_n = 1.0f / 4194304.0f;
  const float mean = stats[o * 2] * inv_n;
  float var = stats[o * 2 + 1] * inv_n - mean * mean;
  var = fmaxf(var, 0.0f);
  const float inv = rsqrtf(var + 1e-5f);
  const float g = gamma[o] * inv;
  const float sh = beta[o] - mean * g;
  float f[8];
  ld8f(outp + e0, f);
#pragma unroll
  for (int t = 0; t < 8; ++t) f[t] = fmaf(f[t], g, sh);
  st8f_nt(outp + e0, f);
}

extern "C" void kernel_launch(void* const* d_in, const int* in_sizes, int n_in,
                              void* d_out, int out_size, void* d_ws, size_t ws_size,
                              hipStream_t stream) {
  const float* A  = (const float*)d_in[0];
  const float* P1 = (const float*)d_in[1];
  const float* P2 = (const float*)d_in[2];
  const float* P3 = (const float*)d_in[3];
  const float* P4 = (const float*)d_in[4];
  const float* P5 = (const float*)d_in[5];
  const float* Wq = (const float*)d_in[6];
  const float* Wk = (const float*)d_in[7];
  const float* gamma = (const float*)d_in[8];
  const float* beta  = (const float*)d_in[9];
  float* outp = (float*)d_out;

  float* stats = (float*)d_ws;
  float* mcab = (float*)((char*)d_ws + 256);  // 4 MB: mc then a2pre in place

  hipLaunchKernelGGL(k1a_mmean, dim3(512), dim3(1024), 0, stream, A, mcab, stats);
  hipLaunchKernelGGL(k1b_p2, dim3(512), dim3(256), 0, stream, mcab, P2);

  // Cooperative fused main+BN. On any launch error, fall back to the proven
  // two-kernel path (nothing was launched if it fails).
  void* kargs[] = {
    (void*)&A, (void*)&mcab, (void*)&P1, (void*)&P3, (void*)&P4, (void*)&P5,
    (void*)&Wq, (void*)&Wk, (void*)&gamma, (void*)&beta, (void*)&outp,
    (void*)&stats
  };
  hipError_t err = hipLaunchCooperativeKernel(
      (const void*)k2_fused, dim3(512), dim3(256), kargs, 0, stream);
  if (err != hipSuccess) {
    (void)hipGetLastError();  // clear error state
    hipLaunchKernelGGL(k2_main, dim3(2048), dim3(256), 0, stream,
                       A, mcab, P1, P3, P4, P5, Wq, Wk, outp, stats);
    hipLaunchKernelGGL(k3_norm_inplace, dim3(16384), dim3(256), 0, stream,
                       outp, stats, gamma, beta);
  }
}

// Round 7
// 386.549 us; speedup vs baseline: 1.8393x; 1.6770x over previous
//
#include <hip/hip_runtime.h>
#include <hip/hip_fp16.h>
#include <hip/hip_cooperative_groups.h>

namespace cg = cooperative_groups;

// layer_3d_dep_53300544143949 — MI355X (gfx950)
// B=64, C=8, O=8, M=32, K=32, NR=8, NT=8. All inputs and output FLOAT32.
// R10 = R9 resubmit (R9 bench was an infra flake: no timing data at all) + a
// host-side occupancy guard so a non-co-resident coop grid falls back instead
// of deadlocking in grid.sync.
//   R8 post-mortem: psum/psq[8] live across the 4x mi loop under the empirical
//   VGPR cap of __launch_bounds__(256,2)=128 forced in-loop spill (~150MB extra
//   FETCH+WRITE each, VALUBusy 10.7%). Fixes:
//     (1) stats accumulate into LDS sred per-mi (lane0 +=, race-free) ->
//         psum/psq are mi-local; phase-1 pressure == proven k2_main.
//     (2) __launch_bounds__(256,1) -> cap 256; VGPR in (128,256] still gives
//         2 waves/SIMD = 2 blocks/CU = coop co-residency for grid 512.
//     (3) phase 2 batches 8 chunk-reads before ONE barrier per mi.
//   k1a: m-mean reduce -> mc (ws, 4MB) + stats zero
//   k1b: in-place P2 transform mc -> a2pre
//   k2_fused (cooperative, grid 512 = (b, m-group-of-4), 256 thr):
//     phase 1: 4x per-m pipeline; per (mi,o) pack fp16 -> 16B into own 8KB
//              output chunk (b,o,m); per-mi stats -> sred
//     16 atomics; __threadfence + grid.sync + __threadfence
//     phase 2: per mi: read 8x16B staging, barrier, write 8x32B f32 NT.
//   Fallback (occupancy < 2/CU or coop launch error): k2_main + k3 (387us).
// ws: [0,256) stats | [256, 256+4MB) mc/a2pre f32   (ws_size in [4.19,4.33)MB)

using u16 = unsigned short;
using u32 = unsigned int;
typedef float f32x4 __attribute__((ext_vector_type(4)));

__device__ __forceinline__ void ld8f(const float* p, float* f) {
  float4 a = *(const float4*)p;
  float4 b = *(const float4*)(p + 4);
  f[0] = a.x; f[1] = a.y; f[2] = a.z; f[3] = a.w;
  f[4] = b.x; f[5] = b.y; f[6] = b.z; f[7] = b.w;
}
__device__ __forceinline__ void st8f(float* p, const float* f) {
  *(float4*)p = make_float4(f[0], f[1], f[2], f[3]);
  *(float4*)(p + 4) = make_float4(f[4], f[5], f[6], f[7]);
}
__device__ __forceinline__ void st8f_nt(float* p, const float* f) {
  f32x4 a = {f[0], f[1], f[2], f[3]};
  f32x4 b = {f[4], f[5], f[6], f[7]};
  __builtin_nontemporal_store(a, (f32x4*)p);
  __builtin_nontemporal_store(b, (f32x4*)(p + 4));
}
__device__ __forceinline__ u16 f2h(float f) {
  __half h = __float2half_rn(f);
  return *(u16*)&h;
}
__device__ __forceinline__ float h2f(u16 x) {
  __half h = *(__half*)&x;
  return __half2float(h);
}
__device__ __forceinline__ float fast_tanh(float x) {
  float e = __expf(2.0f * x);
  return 1.0f - 2.0f / (e + 1.0f);
}

// ---------------- k1a: m-mean reduce (1024 thr, LDS reduce) ----------------
__global__ __launch_bounds__(1024) void k1a_mmean(
    const float* __restrict__ A, float* __restrict__ mcab,
    float* __restrict__ stats) {
  __shared__ float red[4][256][9];
  const int b = blockIdx.x >> 3;
  const int c = blockIdx.x & 7;
  const int tid = threadIdx.x;
  if (blockIdx.x == 0 && tid < 16) stats[tid] = 0.0f;
  const int mh = tid >> 8;
  const int jt = tid & 255;
  const float* base = A + (size_t)(b * 8 + c) * 65536 + (size_t)mh * 8 * 2048 + jt * 8;
  float acc[8];
#pragma unroll
  for (int t = 0; t < 8; ++t) acc[t] = 0.0f;
#pragma unroll
  for (int m = 0; m < 8; ++m) {
    float ar[8];
    ld8f(base + m * 2048, ar);
#pragma unroll
    for (int t = 0; t < 8; ++t) acc[t] += ar[t];
  }
#pragma unroll
  for (int t = 0; t < 8; ++t) red[mh][jt][t] = acc[t];
  __syncthreads();
  if (mh == 0) {
    float s[8];
#pragma unroll
    for (int t = 0; t < 8; ++t)
      s[t] = (red[0][jt][t] + red[1][jt][t] + red[2][jt][t] + red[3][jt][t]) *
             (1.0f / 32.0f);
    st8f(mcab + (size_t)(b * 8 + c) * 2048 + jt * 8, s);
  }
}

// ---------------- k1b: in-place P2 transform mc -> a2pre ----------------
__global__ void k1b_p2(float* __restrict__ mcab, const float* __restrict__ P2) {
  const int b = blockIdx.x >> 3;
  const int j = (blockIdx.x & 7) * 256 + threadIdx.x;
  float mc[8];
#pragma unroll
  for (int c = 0; c < 8; ++c) mc[c] = mcab[(size_t)(b * 8 + c) * 2048 + j];
  float a2[8];
#pragma unroll
  for (int o = 0; o < 8; ++o) {
    float s = 0.0f;
#pragma unroll
    for (int c = 0; c < 8; ++c) s = fmaf(P2[o * 8 + c], mc[c], s);
    a2[o] = 0.1f * s;
  }
#pragma unroll
  for (int o = 0; o < 8; ++o) mcab[(size_t)(b * 8 + o) * 2048 + j] = a2[o];
}

// ---------------- k2_fused: main + BN, cooperative, d_out staging ----------------
// grid 512 = (b<<3)|mg; 256 thr. Each block does m = mg*4 + {0..3}.
__global__ __launch_bounds__(256, 1) void k2_fused(
    const float* __restrict__ A,
    const float* __restrict__ a2pre,
    const float* __restrict__ P1,
    const float* __restrict__ P3,
    const float* __restrict__ P4,
    const float* __restrict__ P5,
    const float* __restrict__ Wq,
    const float* __restrict__ Wk,
    const float* __restrict__ gamma,
    const float* __restrict__ beta,
    float* __restrict__ outp,
    float* __restrict__ stats) {
  __shared__ float qb[8 * 260];
  __shared__ float kb[8 * 260];
  __shared__ float vb[8 * 260];
  __shared__ float a5b[8 * 260];
  __shared__ float sred[64];

  const int tid = threadIdx.x;
  const int b = blockIdx.x >> 3;
  const int mg = blockIdx.x & 7;
  const int k = tid >> 3;
  const int r = tid & 7;

  if (tid < 64) sred[tid] = 0.0f;  // first use is after mi=0's barriers

#pragma unroll 1
  for (int mi = 0; mi < 4; ++mi) {
    const int m = mg * 4 + mi;

    float acc[8][8];
    float acc3[8];
    float qv[8], kv[8], vv[8];
#pragma unroll
    for (int o = 0; o < 8; ++o) {
      acc3[o] = 0.0f;
#pragma unroll
      for (int t = 0; t < 8; ++t) acc[o][t] = 0.0f;
    }
#pragma unroll
    for (int t = 0; t < 8; ++t) { qv[t] = 0.0f; kv[t] = 0.0f; vv[t] = 0.0f; }

#pragma unroll
    for (int c = 0; c < 8; ++c) {
      float ar[8];
      ld8f(A + ((size_t)((b * 8 + c) * 32 + m) * 2048 + tid * 8), ar);
      float trc[8];
#pragma unroll
      for (int t = 0; t < 8; ++t) {
        float x = ar[t];
        x += __shfl_xor(x, 1, 64);
        x += __shfl_xor(x, 2, 64);
        x += __shfl_xor(x, 4, 64);
        trc[t] = x * 0.125f;
      }
      const float mtc = (ar[0] + ar[1] + ar[2] + ar[3] +
                         ar[4] + ar[5] + ar[6] + ar[7]) * 0.125f;
#pragma unroll
      for (int o = 0; o < 8; ++o) {
        const float w1 = P1[o * 8 + c];
        const float w4 = 0.5f * P4[o * 8 + c];
        acc3[o] = fmaf(0.1f * P3[o * 8 + c], mtc, acc3[o]);
#pragma unroll
        for (int t = 0; t < 8; ++t)
          acc[o][t] = fmaf(w1, ar[t], fmaf(w4, trc[t], acc[o][t]));
      }
      const float wq = Wq[r * 8 + c];
      const float wk = Wk[r * 8 + c];
      const float wv = P5[r * 8 + c];
#pragma unroll
      for (int t = 0; t < 8; ++t) {
        qv[t] = fmaf(wq, trc[t], qv[t]);
        kv[t] = fmaf(wk, trc[t], kv[t]);
        vv[t] = fmaf(wv, trc[t], vv[t]);
      }
    }

#pragma unroll
    for (int o = 0; o < 8; ++o) {
      float a2v[8];
      ld8f(a2pre + ((size_t)(b * 8 + o) * 2048 + tid * 8), a2v);
#pragma unroll
      for (int t = 0; t < 8; ++t) acc[o][t] += a2v[t] + acc3[o];
    }

    st8f(&qb[r * 260 + k * 8], qv);
    st8f(&kb[r * 260 + k * 8], kv);
    st8f(&vb[r * 260 + k * 8], vv);
    __syncthreads();

    {
      const int o = tid >> 5;
      const int kq = (tid >> 2) & 7;
      const int lo = tid & 3;
      float qf[4][8];
#pragma unroll
      for (int kl = 0; kl < 4; ++kl)
        ld8f(&qb[o * 260 + (kq * 4 + kl) * 8], qf[kl]);
      float a5p[4][8];
#pragma unroll
      for (int kl = 0; kl < 4; ++kl)
#pragma unroll
        for (int t = 0; t < 8; ++t) a5p[kl][t] = 0.0f;

#pragma unroll
      for (int ll = 0; ll < 8; ++ll) {
        const int l = lo * 8 + ll;
        float krw[8];
        ld8f(&kb[o * 260 + l * 8], krw);
        float al[4];
#pragma unroll
        for (int kl = 0; kl < 4; ++kl) {
          float s = 0.0f;
#pragma unroll
          for (int t = 0; t < 8; ++t) s = fmaf(qf[kl][t], krw[t], s);
          al[kl] = fast_tanh(s * 0.125f);
        }
        float vrw[8];
        ld8f(&vb[o * 260 + l * 8], vrw);
#pragma unroll
        for (int kl = 0; kl < 4; ++kl)
#pragma unroll
          for (int t = 0; t < 8; ++t)
            a5p[kl][t] = fmaf(al[kl], vrw[t], a5p[kl][t]);
      }
#pragma unroll
      for (int kl = 0; kl < 4; ++kl)
#pragma unroll
        for (int t = 0; t < 8; ++t) {
          float x = a5p[kl][t];
          x += __shfl_xor(x, 1, 64);
          x += __shfl_xor(x, 2, 64);
          a5p[kl][t] = x * 0.0625f;
        }
#pragma unroll
      for (int kl = 0; kl < 4; ++kl) {
        const float w0 = lo == 0 ? a5p[kl][0] : lo == 1 ? a5p[kl][2]
                        : lo == 2 ? a5p[kl][4] : a5p[kl][6];
        const float w1 = lo == 0 ? a5p[kl][1] : lo == 1 ? a5p[kl][3]
                        : lo == 2 ? a5p[kl][5] : a5p[kl][7];
        *(float2*)&a5b[o * 260 + (kq * 4 + kl) * 8 + lo * 2] = make_float2(w0, w1);
      }
    }
    __syncthreads();

    // Epilogue: +A5, ReLU, per-mi stats, pack fp16 -> stage into own chunk.
    float psum[8], psq[8];  // mi-local: dies before next iteration
#pragma unroll
    for (int o = 0; o < 8; ++o) { psum[o] = 0.0f; psq[o] = 0.0f; }
#pragma unroll
    for (int o = 0; o < 8; ++o) {
      float a5f[8];
      ld8f(&a5b[o * 260 + k * 8], a5f);
      float x8[8];
#pragma unroll
      for (int t = 0; t < 8; ++t) {
        float x = acc[o][t] + a5f[t];
        x = fmaxf(x, 0.0f);
        psum[o] += x;
        psq[o] = fmaf(x, x, psq[o]);
        x8[t] = x;
      }
      uint4 u;
      u.x = (u32)f2h(x8[0]) | ((u32)f2h(x8[1]) << 16);
      u.y = (u32)f2h(x8[2]) | ((u32)f2h(x8[3]) << 16);
      u.z = (u32)f2h(x8[4]) | ((u32)f2h(x8[5]) << 16);
      u.w = (u32)f2h(x8[6]) | ((u32)f2h(x8[7]) << 16);
      const size_t Eb = (size_t)((b * 8 + o) * 32 + m) * 2048;
      *(uint4*)((u32*)outp + Eb + 4 * tid) = u;  // cached: re-read in phase 2
    }
    // wave butterfly, then lane0 accumulates into sred (same-thread +=,
    // no cross-wave aliasing -> no barrier needed here)
#pragma unroll
    for (int o = 0; o < 8; ++o) {
      float s = psum[o], q = psq[o];
#pragma unroll
      for (int mask = 32; mask >= 1; mask >>= 1) {
        s += __shfl_xor(s, mask, 64);
        q += __shfl_xor(q, mask, 64);
      }
      psum[o] = s; psq[o] = q;
    }
    if ((tid & 63) == 0) {
      const int wid = tid >> 6;
#pragma unroll
      for (int o = 0; o < 8; ++o) {
        sred[wid * 16 + o * 2] += psum[o];
        sred[wid * 16 + o * 2 + 1] += psq[o];
      }
    }
  }

  __syncthreads();
  if (tid < 16) {
    float s = sred[tid] + sred[16 + tid] + sred[32 + tid] + sred[48 + tid];
    atomicAdd(&stats[tid], s);
  }

  // ---- grid-wide sync: all stats atomics + staging stores complete & visible ----
  __threadfence();
  cg::this_grid().sync();
  __threadfence();

  // ---- phase 2: per-chunk in-place fp16 -> normalized f32 ----
  float gg[8], shh[8];
#pragma unroll
  for (int o = 0; o < 8; ++o) {
    const float inv_n = 1.0f / 4194304.0f;
    const float mean = stats[o * 2] * inv_n;
    float var = stats[o * 2 + 1] * inv_n - mean * mean;
    var = fmaxf(var, 0.0f);
    const float inv = rsqrtf(var + 1e-5f);
    gg[o] = gamma[o] * inv;
    shh[o] = beta[o] - mean * gg[o];
  }
#pragma unroll 1
  for (int mi = 0; mi < 4; ++mi) {
    const int m = mg * 4 + mi;
    uint4 u[8];
#pragma unroll
    for (int o = 0; o < 8; ++o) {
      const size_t Eb = (size_t)((b * 8 + o) * 32 + m) * 2048;
      u[o] = *(const uint4*)((const u32*)outp + Eb + 4 * tid);
    }
    __syncthreads();  // all reads (drained by barrier semantics) before writes
#pragma unroll
    for (int o = 0; o < 8; ++o) {
      const size_t Eb = (size_t)((b * 8 + o) * 32 + m) * 2048;
      float f[8];
      f[0] = h2f((u16)(u[o].x & 0xffffu)); f[1] = h2f((u16)(u[o].x >> 16));
      f[2] = h2f((u16)(u[o].y & 0xffffu)); f[3] = h2f((u16)(u[o].y >> 16));
      f[4] = h2f((u16)(u[o].z & 0xffffu)); f[5] = h2f((u16)(u[o].z >> 16));
      f[6] = h2f((u16)(u[o].w & 0xffffu)); f[7] = h2f((u16)(u[o].w >> 16));
#pragma unroll
      for (int t = 0; t < 8; ++t) f[t] = fmaf(f[t], gg[o], shh[o]);
      st8f_nt(outp + Eb + (size_t)tid * 8, f);
    }
  }
}

// ---------------- fallback: k2 f32 -> d_out ----------------
__global__ __launch_bounds__(256, 2) void k2_main(
    const float* __restrict__ A,
    const float* __restrict__ a2pre,
    const float* __restrict__ P1,
    const float* __restrict__ P3,
    const float* __restrict__ P4,
    const float* __restrict__ P5,
    const float* __restrict__ Wq,
    const float* __restrict__ Wk,
    float* __restrict__ outp,
    float* __restrict__ stats) {
  __shared__ float qb[8 * 260];
  __shared__ float kb[8 * 260];
  __shared__ float vb[8 * 260];
  __shared__ float a5b[8 * 260];
  __shared__ float sred[64];

  const int tid = threadIdx.x;
  const int b = blockIdx.x >> 5;
  const int m = blockIdx.x & 31;
  const int k = tid >> 3;
  const int r = tid & 7;

  float acc[8][8];
  float acc3[8];
  float qv[8], kv[8], vv[8];
#pragma unroll
  for (int o = 0; o < 8; ++o) {
    acc3[o] = 0.0f;
#pragma unroll
    for (int t = 0; t < 8; ++t) acc[o][t] = 0.0f;
  }
#pragma unroll
  for (int t = 0; t < 8; ++t) { qv[t] = 0.0f; kv[t] = 0.0f; vv[t] = 0.0f; }

#pragma unroll
  for (int c = 0; c < 8; ++c) {
    float ar[8];
    ld8f(A + ((size_t)((b * 8 + c) * 32 + m) * 2048 + tid * 8), ar);
    float trc[8];
#pragma unroll
    for (int t = 0; t < 8; ++t) {
      float x = ar[t];
      x += __shfl_xor(x, 1, 64);
      x += __shfl_xor(x, 2, 64);
      x += __shfl_xor(x, 4, 64);
      trc[t] = x * 0.125f;
    }
    const float mtc = (ar[0] + ar[1] + ar[2] + ar[3] +
                       ar[4] + ar[5] + ar[6] + ar[7]) * 0.125f;
#pragma unroll
    for (int o = 0; o < 8; ++o) {
      const float w1 = P1[o * 8 + c];
      const float w4 = 0.5f * P4[o * 8 + c];
      acc3[o] = fmaf(0.1f * P3[o * 8 + c], mtc, acc3[o]);
#pragma unroll
      for (int t = 0; t < 8; ++t)
        acc[o][t] = fmaf(w1, ar[t], fmaf(w4, trc[t], acc[o][t]));
    }
    const float wq = Wq[r * 8 + c];
    const float wk = Wk[r * 8 + c];
    const float wv = P5[r * 8 + c];
#pragma unroll
    for (int t = 0; t < 8; ++t) {
      qv[t] = fmaf(wq, trc[t], qv[t]);
      kv[t] = fmaf(wk, trc[t], kv[t]);
      vv[t] = fmaf(wv, trc[t], vv[t]);
    }
  }

#pragma unroll
  for (int o = 0; o < 8; ++o) {
    float a2v[8];
    ld8f(a2pre + ((size_t)(b * 8 + o) * 2048 + tid * 8), a2v);
#pragma unroll
    for (int t = 0; t < 8; ++t) acc[o][t] += a2v[t] + acc3[o];
  }

  st8f(&qb[r * 260 + k * 8], qv);
  st8f(&kb[r * 260 + k * 8], kv);
  st8f(&vb[r * 260 + k * 8], vv);
  __syncthreads();

  {
    const int o = tid >> 5;
    const int kq = (tid >> 2) & 7;
    const int lo = tid & 3;
    float qf[4][8];
#pragma unroll
    for (int kl = 0; kl < 4; ++kl)
      ld8f(&qb[o * 260 + (kq * 4 + kl) * 8], qf[kl]);
    float a5p[4][8];
#pragma unroll
    for (int kl = 0; kl < 4; ++kl)
#pragma unroll
      for (int t = 0; t < 8; ++t) a5p[kl][t] = 0.0f;

#pragma unroll
    for (int ll = 0; ll < 8; ++ll) {
      const int l = lo * 8 + ll;
      float krw[8];
      ld8f(&kb[o * 260 + l * 8], krw);
      float al[4];
#pragma unroll
      for (int kl = 0; kl < 4; ++kl) {
        float s = 0.0f;
#pragma unroll
        for (int t = 0; t < 8; ++t) s = fmaf(qf[kl][t], krw[t], s);
        al[kl] = fast_tanh(s * 0.125f);
      }
      float vrw[8];
      ld8f(&vb[o * 260 + l * 8], vrw);
#pragma unroll
      for (int kl = 0; kl < 4; ++kl)
#pragma unroll
        for (int t = 0; t < 8; ++t)
          a5p[kl][t] = fmaf(al[kl], vrw[t], a5p[kl][t]);
    }
#pragma unroll
    for (int kl = 0; kl < 4; ++kl)
#pragma unroll
      for (int t = 0; t < 8; ++t) {
        float x = a5p[kl][t];
        x += __shfl_xor(x, 1, 64);
        x += __shfl_xor(x, 2, 64);
        a5p[kl][t] = x * 0.0625f;
      }
#pragma unroll
    for (int kl = 0; kl < 4; ++kl) {
      const float w0 = lo == 0 ? a5p[kl][0] : lo == 1 ? a5p[kl][2]
                      : lo == 2 ? a5p[kl][4] : a5p[kl][6];
      const float w1 = lo == 0 ? a5p[kl][1] : lo == 1 ? a5p[kl][3]
                      : lo == 2 ? a5p[kl][5] : a5p[kl][7];
      *(float2*)&a5b[o * 260 + (kq * 4 + kl) * 8 + lo * 2] = make_float2(w0, w1);
    }
  }
  __syncthreads();

  float psum[8], psq[8];
#pragma unroll
  for (int o = 0; o < 8; ++o) { psum[o] = 0.0f; psq[o] = 0.0f; }
  const size_t outbase = (size_t)(b * 256 + m) * 2048 + tid * 8;
#pragma unroll
  for (int o = 0; o < 8; ++o) {
    float a5f[8];
    ld8f(&a5b[o * 260 + k * 8], a5f);
    float x8[8];
#pragma unroll
    for (int t = 0; t < 8; ++t) {
      float x = acc[o][t] + a5f[t];
      x = fmaxf(x, 0.0f);
      psum[o] += x;
      psq[o] = fmaf(x, x, psq[o]);
      x8[t] = x;
    }
    st8f(outp + (outbase + (size_t)o * 65536), x8);
  }
#pragma unroll
  for (int o = 0; o < 8; ++o) {
    float s = psum[o], q = psq[o];
#pragma unroll
    for (int mask = 32; mask >= 1; mask >>= 1) {
      s += __shfl_xor(s, mask, 64);
      q += __shfl_xor(q, mask, 64);
    }
    psum[o] = s; psq[o] = q;
  }
  const int lane = tid & 63;
  const int wid = tid >> 6;
  if (lane == 0) {
#pragma unroll
    for (int o = 0; o < 8; ++o) {
      sred[wid * 16 + o * 2] = psum[o];
      sred[wid * 16 + o * 2 + 1] = psq[o];
    }
  }
  __syncthreads();
  if (tid < 16) {
    float s = sred[tid] + sred[16 + tid] + sred[32 + tid] + sred[48 + tid];
    atomicAdd(&stats[tid], s);
  }
}

// ---------------- fallback: BN in place ----------------
__global__ void k3_norm_inplace(float* __restrict__ outp,
                                const float* __restrict__ stats,
                                const float* __restrict__ gamma,
                                const float* __restrict__ beta) {
  const int idx = blockIdx.x * 256 + threadIdx.x;
  const size_t e0 = (size_t)idx * 8;
  const int o = (int)(e0 >> 16) & 7;
  const float inv_n = 1.0f / 4194304.0f;
  const float mean = stats[o * 2] * inv_n;
  float var = stats[o * 2 + 1] * inv_n - mean * mean;
  var = fmaxf(var, 0.0f);
  const float inv = rsqrtf(var + 1e-5f);
  const float g = gamma[o] * inv;
  const float sh = beta[o] - mean * g;
  float f[8];
  ld8f(outp + e0, f);
#pragma unroll
  for (int t = 0; t < 8; ++t) f[t] = fmaf(f[t], g, sh);
  st8f_nt(outp + e0, f);
}

extern "C" void kernel_launch(void* const* d_in, const int* in_sizes, int n_in,
                              void* d_out, int out_size, void* d_ws, size_t ws_size,
                              hipStream_t stream) {
  const float* A  = (const float*)d_in[0];
  const float* P1 = (const float*)d_in[1];
  const float* P2 = (const float*)d_in[2];
  const float* P3 = (const float*)d_in[3];
  const float* P4 = (const float*)d_in[4];
  const float* P5 = (const float*)d_in[5];
  const float* Wq = (const float*)d_in[6];
  const float* Wk = (const float*)d_in[7];
  const float* gamma = (const float*)d_in[8];
  const float* beta  = (const float*)d_in[9];
  float* outp = (float*)d_out;

  float* stats = (float*)d_ws;
  float* mcab = (float*)((char*)d_ws + 256);  // 4 MB: mc then a2pre in place

  hipLaunchKernelGGL(k1a_mmean, dim3(512), dim3(1024), 0, stream, A, mcab, stats);
  hipLaunchKernelGGL(k1b_p2, dim3(512), dim3(256), 0, stream, mcab, P2);

  // Occupancy guard: only take the cooperative path if all 512 blocks provably
  // co-reside (needs >= 2 blocks/CU on 256 CUs). Host query; graph-capture-safe.
  int maxBlocksPerCU = 0;
  hipError_t qerr = hipOccupancyMaxActiveBlocksPerMultiprocessor(
      &maxBlocksPerCU, (const void*)k2_fused, 256, 0);
  bool coop_ok = (qerr == hipSuccess) && (maxBlocksPerCU >= 2);

  hipError_t err = hipErrorUnknown;
  if (coop_ok) {
    void* kargs[] = {
      (void*)&A, (void*)&mcab, (void*)&P1, (void*)&P3, (void*)&P4, (void*)&P5,
      (void*)&Wq, (void*)&Wk, (void*)&gamma, (void*)&beta, (void*)&outp,
      (void*)&stats
    };
    err = hipLaunchCooperativeKernel(
        (const void*)k2_fused, dim3(512), dim3(256), kargs, 0, stream);
  }
  if (err != hipSuccess) {
    (void)hipGetLastError();  // clear error state
    hipLaunchKernelGGL(k2_main, dim3(2048), dim3(256), 0, stream,
                       A, mcab, P1, P3, P4, P5, Wq, Wk, outp, stats);
    hipLaunchKernelGGL(k3_norm_inplace, dim3(16384), dim3(256), 0, stream,
                       outp, stats, gamma, beta);
  }
}